// Round 10
// baseline (1265.526 us; speedup 1.0000x reference)
//
#include <hip/hip_runtime.h>

#define LOG2E 1.44269504088896f

typedef _Float16 half8  __attribute__((ext_vector_type(8)));
typedef _Float16 half4v __attribute__((ext_vector_type(4)));
typedef float    floatx4 __attribute__((ext_vector_type(4)));

// ---------------- workspace layout (bytes) ----------------
// kd:       [1024 subtrees][64 rows][64 half]  swizzled   (8 MB)
// vt:       [1024 subtrees][64 vrow][64 half]  swizzled   (8 MB)
// partials: [64 groups][2048 b][64 v] fp16                (16.78 MB)
// total = 33554432 bytes exactly (proven available)
#define WS_KD   0u
#define WS_VT   8388608u
#define WS_PART 16777216u

__device__ __forceinline__ floatx4 mfma16(half8 a, half8 b, floatx4 c) {
    return __builtin_amdgcn_mfma_f32_16x16x32_f16(a, b, c, 0, 0, 0);
}

__device__ __forceinline__ float sigmf(float d) {
    return __builtin_amdgcn_rcpf(1.0f + __builtin_amdgcn_exp2f(d * (-LOG2E)));
}

// async global->LDS, 16B per lane; dst is wave-uniform (HW adds lane*16)
__device__ __forceinline__ void gl_lds16(const void* gsrc, void* ldst) {
    __builtin_amdgcn_global_load_lds(
        (const __attribute__((address_space(1))) unsigned int*)gsrc,
        (__attribute__((address_space(3))) unsigned int*)ldst,
        16, 0, 0);
}

// ================= kernel 1: prep (kd + vt) =================
// 1024 blocks: block bid does subtree bid's V^T + 512 kd items.
__global__ __launch_bounds__(256)
void k_prep(const float* __restrict__ tkey, const float* __restrict__ tval,
            char* __restrict__ ws)
{
    __shared__ _Float16 sT[64 * 72];   // [dim][leaf], +8 pad
    const int bid = blockIdx.x, tid = threadIdx.x;

    // ---- vt for subtree s = bid ----
    {
        const int l = tid >> 2, part = tid & 3;
        const floatx4* vp = (const floatx4*)(tval + ((size_t)bid * 64 + l) * 64) + part * 4;
        #pragma unroll
        for (int t4 = 0; t4 < 4; ++t4) {
            floatx4 f = vp[t4];
            #pragma unroll
            for (int e = 0; e < 4; ++e)
                sT[(part * 16 + t4 * 4 + e) * 72 + l] = (_Float16)f[e];
        }
    }
    __syncthreads();
    {
        const int v = tid >> 2, q4 = tid & 3;
        half8 x0 = *(const half8*)(sT + v * 72 + 16 * q4);
        half8 x1 = *(const half8*)(sT + v * 72 + 16 * q4 + 8);
        char* base = ws + WS_VT + (size_t)bid * 8192 + v * 128;
        const int swz = (v & 7) << 4;
        *(half8*)(base + ((q4 * 32)      ^ swz)) = x0;
        *(half8*)(base + ((q4 * 32 + 16) ^ swz)) = x1;
    }

    // ---- kd: 2 items per thread (1024 blocks x 512 = 524288 items) ----
    #pragma unroll
    for (int k = 0; k < 2; ++k) {
        const int gt  = bid * 512 + k * 256 + tid;
        const int rid = gt >> 3, part = gt & 7;
        const int s = rid >> 6, j = rid & 63;
        const size_t dst = (size_t)WS_KD + (size_t)s * 8192 + j * 128 + ((part * 16) ^ ((j & 7) << 4));
        half8 out;
        if (j < 63) {
            const int u = j + 1;
            const int f = 31 - __builtin_clz(u);
            const int i = u - (1 << f);
            const int gidx = ((1 << (10 + f)) - 1) + (s << f) + i;
            const floatx4* kp = (const floatx4*)(tkey + (size_t)gidx * 128) + part * 2;
            floatx4 a0 = kp[0], a1 = kp[1];
            floatx4 b0 = kp[16], b1 = kp[17];
            #pragma unroll
            for (int e = 0; e < 4; ++e) {
                out[e]     = (_Float16)(a0[e] - b0[e]);
                out[4 + e] = (_Float16)(a1[e] - b1[e]);
            }
        } else {
            #pragma unroll
            for (int e = 0; e < 8; ++e) out[e] = (_Float16)0.f;
        }
        *(half8*)(ws + dst) = out;
    }
}

// ================= kernel 2: main fused attention =================
// grid 1024 = 64 g x 16 tb (128 batch rows per block), 256 threads.
// Same arithmetic as the round-8 kernel (swapped GEMM1, batch-major sPT,
// vector descent); LDS 43008 B -> 3 blocks/CU = 12 waves/CU.
// NOTE: min-waves arg MUST stay 2 — (…,4) caps VGPR at 64 and spills
// (rounds 2/6/9: scratch traffic ballooned FETCH/WRITE).
__global__ __launch_bounds__(256, 2)
void k_main(const float* __restrict__ q,
            const float* __restrict__ tkey,
            const char* __restrict__ wsc,
            _Float16* __restrict__ pout)
{
    __shared__ _Float16 sA[128 * 64];   // q tile / leaf probs / epilogue transpose (swizzled, stride 64)
    __shared__ _Float16 sPT[128 * 72];  // node probs [batch][node], stride 72 halfs (16B-aligned rows)
    __shared__ _Float16 sB[64 * 64];    // kdiff (swizzled rows)

    const int tid  = threadIdx.x;
    const int w    = tid >> 6;          // 0..3
    const int lane = tid & 63;
    const int lm   = lane & 15;
    const int quad = lane >> 4;
    const int xcd  = blockIdx.x & 7;
    const int ix   = blockIdx.x >> 3;
    const int g    = xcd * 8 + (ix >> 4);   // 0..63
    const int tb   = ix & 15;               // 0..15

    // ---- in-kernel prefix kdiff -> sB rows 0..31 (one-time, swizzled) ----
    {
        const int j = tid >> 3, part = tid & 7;
        int gidx = -1;
        if (j < 6) {
            gidx = (1 << j) - 1 + (g >> (6 - j));
        } else if (j < 21) {
            const int u = j - 5;
            const int e = 31 - __builtin_clz(u);
            const int i = u - (1 << e);
            gidx = ((1 << (6 + e)) - 1) + (g << e) + i;
        }
        half8 out;
        if (gidx >= 0) {
            const floatx4* kp = (const floatx4*)(tkey + (size_t)gidx * 128) + part * 2;
            floatx4 a0 = kp[0], a1 = kp[1];
            floatx4 b0 = kp[16], b1 = kp[17];
            #pragma unroll
            for (int e = 0; e < 4; ++e) {
                out[e]     = (_Float16)(a0[e] - b0[e]);
                out[4 + e] = (_Float16)(a1[e] - b1[e]);
            }
        } else {
            #pragma unroll
            for (int e = 0; e < 8; ++e) out[e] = (_Float16)0.f;
        }
        *(half8*)(sB + j * 64 + ((part * 8) ^ ((j & 7) << 3))) = out;
    }

    // ---- q tile: 128 rows x 64 fp32 -> fp16 in sA (swizzled, stride 64) ----
    {
        const int r = tid >> 1, hh = tid & 1;
        const floatx4* qp = (const floatx4*)(q + (size_t)(tb * 128 + r) * 64 + hh * 32);
        const int sw = (r & 7) << 3;
        #pragma unroll
        for (int t4 = 0; t4 < 4; ++t4) {
            floatx4 f0 = qp[2 * t4], f1 = qp[2 * t4 + 1];
            half8 hv;
            #pragma unroll
            for (int e = 0; e < 4; ++e) { hv[e] = (_Float16)f0[e]; hv[4 + e] = (_Float16)f1[e]; }
            *(half8*)(sA + r * 64 + ((hh * 32 + t4 * 8) ^ sw)) = hv;
        }
    }
    __syncthreads();

    // q fragments (persist): wave w owns batch rows 32w+16m+lm, m=0..1
    half8 qA[2][2];
    #pragma unroll
    for (int m = 0; m < 2; ++m) {
        const int rA = 32 * w + 16 * m + lm;
        const int sw = (lm & 7) << 3;          // rA&7 == lm&7
        #pragma unroll
        for (int kt = 0; kt < 2; ++kt)
            qA[m][kt] = *(const half8*)(sA + rA * 64 + ((kt * 32 + quad * 8) ^ sw));
    }

    // prefix GEMM (nodes 0..31), swapped operands: D rows = nodes, cols = batch.
    {
        #pragma unroll
        for (int nt = 0; nt < 2; ++nt) {
            const int row = 16 * nt + lm;
            const int sw = (lm & 7) << 3;
            half8 bf0 = *(const half8*)(sB + row * 64 + ((quad * 8) ^ sw));
            half8 bf1 = *(const half8*)(sB + row * 64 + ((32 + quad * 8) ^ sw));
            floatx4 acc[2];
            #pragma unroll
            for (int m = 0; m < 2; ++m) {
                acc[m][0] = 0.f; acc[m][1] = 0.f; acc[m][2] = 0.f; acc[m][3] = 0.f;
                acc[m] = mfma16(bf0, qA[m][0], acc[m]);
                acc[m] = mfma16(bf1, qA[m][1], acc[m]);
            }
            #pragma unroll
            for (int m = 0; m < 2; ++m) {
                half4v ph;
                #pragma unroll
                for (int r = 0; r < 4; ++r) ph[r] = (_Float16)sigmf(acc[m][r]);
                *(half4v*)(sPT + (32 * w + 16 * m + lm) * 72 + 16 * nt + 4 * quad) = ph;
            }
        }
    }
    __syncthreads();

    // prefix probabilities -> registers (threads bb and bb+128 duplicate batch bb)
    const int bb = tid & 127;
    float pref = 1.f;
    #pragma unroll
    for (int d = 0; d < 6; ++d) {
        float pv = (float)sPT[bb * 72 + d];
        pref *= ((g >> (5 - d)) & 1) ? (1.f - pv) : pv;
    }
    const float p6    = (float)sPT[bb * 72 + 6];
    const float p7_0  = (float)sPT[bb * 72 + 7],  p7_1  = (float)sPT[bb * 72 + 8];
    const float p9_0  = (float)sPT[bb * 72 + 9],  p9_1  = (float)sPT[bb * 72 + 10];
    const float p9_2  = (float)sPT[bb * 72 + 11], p9_3  = (float)sPT[bb * 72 + 12];
    const float p13_0 = (float)sPT[bb * 72 + 13], p13_1 = (float)sPT[bb * 72 + 14];
    const float p13_2 = (float)sPT[bb * 72 + 15], p13_3 = (float)sPT[bb * 72 + 16];
    const float p13_4 = (float)sPT[bb * 72 + 17], p13_5 = (float)sPT[bb * 72 + 18];
    const float p13_6 = (float)sPT[bb * 72 + 19], p13_7 = (float)sPT[bb * 72 + 20];

    floatx4 O[2][4];
    #pragma unroll
    for (int m = 0; m < 2; ++m)
        #pragma unroll
        for (int nt = 0; nt < 4; ++nt) { O[m][nt][0]=0.f; O[m][nt][1]=0.f; O[m][nt][2]=0.f; O[m][nt][3]=0.f; }

    const int qh = tid >> 7;   // 0..1: which pair of qq quadrants this thread descends

    for (int sl = 0; sl < 16; ++sl) {
        const int s = (g << 4) + sl;

        // stage kdiff (8 KB: 4 waves x 2 KB, async DMA) + V fragments to regs
        {
            const char* kd = wsc + WS_KD + (size_t)s * 8192;
            gl_lds16(kd + w * 2048 +        lane * 16, sB + w * 1024);
            gl_lds16(kd + w * 2048 + 1024 + lane * 16, sB + w * 1024 + 512);
        }
        half8 vf[4][2];
        {
            const char* vt = wsc + WS_VT + (size_t)s * 8192;
            #pragma unroll
            for (int nt = 0; nt < 4; ++nt) {
                const int row = 16 * nt + lm;
                const int swz = (lm & 7) << 4;
                #pragma unroll
                for (int kt = 0; kt < 2; ++kt)
                    vf[nt][kt] = *(const half8*)(vt + row * 128 + ((kt * 64 + quad * 16) ^ swz));
            }
        }
        __syncthreads();   // B0: kd landed (barrier drains vmcnt)

        // GEMM1 (swapped) + sigmoid, fused per nt: probs -> sPT[batch][node]
        __builtin_amdgcn_s_setprio(1);
        #pragma unroll
        for (int nt = 0; nt < 4; ++nt) {
            const int row = 16 * nt + lm;
            const int sw = (lm & 7) << 3;
            half8 bf0 = *(const half8*)(sB + row * 64 + ((quad * 8) ^ sw));
            half8 bf1 = *(const half8*)(sB + row * 64 + ((32 + quad * 8) ^ sw));
            floatx4 acc[2];
            #pragma unroll
            for (int m = 0; m < 2; ++m) {
                acc[m][0] = 0.f; acc[m][1] = 0.f; acc[m][2] = 0.f; acc[m][3] = 0.f;
                acc[m] = mfma16(bf0, qA[m][0], acc[m]);
                acc[m] = mfma16(bf1, qA[m][1], acc[m]);
            }
            #pragma unroll
            for (int m = 0; m < 2; ++m) {
                half4v ph;
                #pragma unroll
                for (int r = 0; r < 4; ++r) ph[r] = (_Float16)sigmf(acc[m][r]);
                *(half4v*)(sPT + (32 * w + 16 * m + lm) * 72 + 16 * nt + 4 * quad) = ph;
            }
        }
        __builtin_amdgcn_s_setprio(0);
        __syncthreads();   // B1

        // P0 for this subtree from register prefix probs
        const int a0 = sl >> 3, a1 = sl >> 2, a2 = sl >> 1;
        float P0v = pref * (a0 ? (1.f - p6) : p6);
        { float v7 = a0 ? p7_1 : p7_0;                    P0v *= (a1 & 1) ? (1.f - v7) : v7; }
        { float v9 = (a1 == 0) ? p9_0 : (a1 == 1) ? p9_1 : (a1 == 2) ? p9_2 : p9_3;
                                                          P0v *= (a2 & 1) ? (1.f - v9) : v9; }
        { float vd = (a2 == 0) ? p13_0 : (a2 == 1) ? p13_1 : (a2 == 2) ? p13_2 : (a2 == 3) ? p13_3
                   : (a2 == 4) ? p13_4 : (a2 == 5) ? p13_5 : (a2 == 6) ? p13_6 : p13_7;
                                                          P0v *= (sl & 1) ? (1.f - vd) : vd; }

        // load batch bb's 64-node prob row: 8x ds_read_b128 (paired threads broadcast)
        half8 pr[8];
        #pragma unroll
        for (int t = 0; t < 8; ++t)
            pr[t] = *(const half8*)(sPT + bb * 72 + t * 8);
        #define PN(n) ((float)pr[(n) >> 3][(n) & 7])

        // leaf probabilities -> sA[bb][l] fp16; thread handles 2 of 4 qq quadrants
        {
            #pragma unroll
            for (int qi = 0; qi < 2; ++qi) {
                const int qq = 2 * qh + qi;
                float p0 = PN(0);
                float p1 = PN(1 + (qq >> 1));
                float P2 = P0v * (((qq >> 1) & 1) ? (1.f - p0) : p0)
                               * ((qq & 1) ? (1.f - p1) : p1);
                float p2 = PN(3 + qq);
                float A3[2]; A3[0] = P2 * p2; A3[1] = P2 * (1.f - p2);
                float A4[4];
                #pragma unroll
                for (int c = 0; c < 2; ++c) {
                    float pv = PN(7 + 2 * qq + c);
                    A4[2 * c] = A3[c] * pv; A4[2 * c + 1] = A3[c] * (1.f - pv);
                }
                float A5[8];
                #pragma unroll
                for (int n = 0; n < 4; ++n) {
                    float pv = PN(15 + 4 * qq + n);
                    A5[2 * n] = A4[n] * pv; A5[2 * n + 1] = A4[n] * (1.f - pv);
                }
                half8 lo, hi;
                #pragma unroll
                for (int n = 0; n < 8; ++n) {
                    float pv = PN(31 + 8 * qq + n);
                    float e0 = A5[n] * pv;
                    float e1 = A5[n] * (1.f - pv);
                    if (n < 4) { lo[2 * n] = (_Float16)e0; lo[2 * n + 1] = (_Float16)e1; }
                    else       { hi[2 * (n - 4)] = (_Float16)e0; hi[2 * (n - 4) + 1] = (_Float16)e1; }
                }
                const int sw = (bb & 7) << 3;
                *(half8*)(sA + bb * 64 + ((16 * qq)     ^ sw)) = lo;
                *(half8*)(sA + bb * 64 + ((16 * qq + 8) ^ sw)) = hi;
            }
        }
        #undef PN
        __syncthreads();   // B2

        // GEMM2: O += P @ V  (B-operand from registers)
        {
            half8 af[2][2];
            #pragma unroll
            for (int m = 0; m < 2; ++m) {
                const int rA = 32 * w + 16 * m + lm;
                const int sw = (lm & 7) << 3;
                #pragma unroll
                for (int kt = 0; kt < 2; ++kt)
                    af[m][kt] = *(const half8*)(sA + rA * 64 + ((kt * 32 + quad * 8) ^ sw));
            }
            __builtin_amdgcn_s_setprio(1);
            #pragma unroll
            for (int nt = 0; nt < 4; ++nt)
                #pragma unroll
                for (int kt = 0; kt < 2; ++kt) {
                    O[0][nt] = mfma16(af[0][kt], vf[nt][kt], O[0][nt]);
                    O[1][nt] = mfma16(af[1][kt], vf[nt][kt], O[1][nt]);
                }
            __builtin_amdgcn_s_setprio(0);
        }
    }

    // ---- epilogue: transpose O through sA (swizzled, stride 64), coalesced fp16 stores ----
    __syncthreads();
    #pragma unroll
    for (int m = 0; m < 2; ++m)
        #pragma unroll
        for (int nt = 0; nt < 4; ++nt)
            #pragma unroll
            for (int r = 0; r < 4; ++r) {
                const int row = 32 * w + 16 * m + 4 * quad + r;
                const int col = 16 * nt + lm;
                sA[row * 64 + (col ^ ((row & 7) << 3))] = (_Float16)O[m][nt][r];
            }
    __syncthreads();
    {
        const int row = tid >> 1, hh = tid & 1;
        _Float16* dst = pout + ((size_t)g * 2048 + tb * 128 + row) * 64 + hh * 32;
        const int sw = (row & 7) << 3;
        #pragma unroll
        for (int j = 0; j < 4; ++j)
            *(half8*)(dst + j * 8) = *(const half8*)(sA + row * 64 + ((hh * 32 + j * 8) ^ sw));
    }
}

// ================= kernel 3: reduce 64 fp16 partials -> fp32 out =================
__global__ __launch_bounds__(256)
void k_reduce(const _Float16* __restrict__ part, float* __restrict__ outp)
{
    const int idx = blockIdx.x * 256 + threadIdx.x;  // 0..32767
    float s0 = 0.f, s1 = 0.f, s2 = 0.f, s3 = 0.f;
    #pragma unroll 8
    for (int gg = 0; gg < 64; ++gg) {
        half4v v = *(const half4v*)(part + (size_t)gg * 131072 + (size_t)idx * 4);
        s0 += (float)v[0]; s1 += (float)v[1]; s2 += (float)v[2]; s3 += (float)v[3];
    }
    floatx4 o; o[0] = s0; o[1] = s1; o[2] = s2; o[3] = s3;
    *(floatx4*)(outp + (size_t)idx * 4) = o;
}

extern "C" void kernel_launch(void* const* d_in, const int* in_sizes, int n_in,
                              void* d_out, int out_size, void* d_ws, size_t ws_size,
                              hipStream_t stream)
{
    const float* q  = (const float*)d_in[0];
    const float* tk = (const float*)d_in[1];
    const float* tv = (const float*)d_in[2];
    float* outp = (float*)d_out;
    char*  ws   = (char*)d_ws;
    _Float16* partp = (_Float16*)(ws + WS_PART);

    k_prep  <<<dim3(1024), dim3(256), 0, stream>>>(tk, tv, ws);
    k_main  <<<dim3(1024), dim3(256), 0, stream>>>(q, tk, ws, partp);
    k_reduce<<<dim3(128),  dim3(256), 0, stream>>>(partp, outp);
}

// Round 11
// 176.520 us; speedup vs baseline: 7.1693x; 7.1693x over previous
//
#include <hip/hip_runtime.h>

#define LOG2E 1.44269504088896f

typedef _Float16 half8  __attribute__((ext_vector_type(8)));
typedef _Float16 half4v __attribute__((ext_vector_type(4)));
typedef float    floatx4 __attribute__((ext_vector_type(4)));

// ---------------- workspace layout (bytes) ----------------
// kd:       [1024 subtrees][64 rows][64 half]  swizzled   (8 MB)
// vt:       [1024 subtrees][64 vrow][64 half]  swizzled   (8 MB)
// partials: [64 groups][2048 b][64 v] fp16                (16.78 MB)
// total = 33554432 bytes exactly (proven available)
#define WS_KD   0u
#define WS_VT   8388608u
#define WS_PART 16777216u

__device__ __forceinline__ floatx4 mfma16(half8 a, half8 b, floatx4 c) {
    return __builtin_amdgcn_mfma_f32_16x16x32_f16(a, b, c, 0, 0, 0);
}

__device__ __forceinline__ float sigmf(float d) {
    return __builtin_amdgcn_rcpf(1.0f + __builtin_amdgcn_exp2f(d * (-LOG2E)));
}

// async global->LDS, 16B per lane; dst is wave-uniform (HW adds lane*16)
__device__ __forceinline__ void gl_lds16(const void* gsrc, void* ldst) {
    __builtin_amdgcn_global_load_lds(
        (const __attribute__((address_space(1))) unsigned int*)gsrc,
        (__attribute__((address_space(3))) unsigned int*)ldst,
        16, 0, 0);
}

// ================= kernel 1: prep (kd + vt) =================
// 1024 blocks: block bid does subtree bid's V^T + 512 kd items.
__global__ __launch_bounds__(256)
void k_prep(const float* __restrict__ tkey, const float* __restrict__ tval,
            char* __restrict__ ws)
{
    __shared__ _Float16 sT[64 * 72];   // [dim][leaf], +8 pad
    const int bid = blockIdx.x, tid = threadIdx.x;

    // ---- vt for subtree s = bid ----
    {
        const int l = tid >> 2, part = tid & 3;
        const floatx4* vp = (const floatx4*)(tval + ((size_t)bid * 64 + l) * 64) + part * 4;
        #pragma unroll
        for (int t4 = 0; t4 < 4; ++t4) {
            floatx4 f = vp[t4];
            #pragma unroll
            for (int e = 0; e < 4; ++e)
                sT[(part * 16 + t4 * 4 + e) * 72 + l] = (_Float16)f[e];
        }
    }
    __syncthreads();
    {
        const int v = tid >> 2, q4 = tid & 3;
        half8 x0 = *(const half8*)(sT + v * 72 + 16 * q4);
        half8 x1 = *(const half8*)(sT + v * 72 + 16 * q4 + 8);
        char* base = ws + WS_VT + (size_t)bid * 8192 + v * 128;
        const int swz = (v & 7) << 4;
        *(half8*)(base + ((q4 * 32)      ^ swz)) = x0;
        *(half8*)(base + ((q4 * 32 + 16) ^ swz)) = x1;
    }

    // ---- kd: 2 items per thread (1024 blocks x 512 = 524288 items) ----
    #pragma unroll
    for (int k = 0; k < 2; ++k) {
        const int gt  = bid * 512 + k * 256 + tid;
        const int rid = gt >> 3, part = gt & 7;
        const int s = rid >> 6, j = rid & 63;
        const size_t dst = (size_t)WS_KD + (size_t)s * 8192 + j * 128 + ((part * 16) ^ ((j & 7) << 4));
        half8 out;
        if (j < 63) {
            const int u = j + 1;
            const int f = 31 - __builtin_clz(u);
            const int i = u - (1 << f);
            const int gidx = ((1 << (10 + f)) - 1) + (s << f) + i;
            const floatx4* kp = (const floatx4*)(tkey + (size_t)gidx * 128) + part * 2;
            floatx4 a0 = kp[0], a1 = kp[1];
            floatx4 b0 = kp[16], b1 = kp[17];
            #pragma unroll
            for (int e = 0; e < 4; ++e) {
                out[e]     = (_Float16)(a0[e] - b0[e]);
                out[4 + e] = (_Float16)(a1[e] - b1[e]);
            }
        } else {
            #pragma unroll
            for (int e = 0; e < 8; ++e) out[e] = (_Float16)0.f;
        }
        *(half8*)(ws + dst) = out;
    }
}

// ================= kernel 2: main fused attention =================
// grid 1024 = 64 g x 16 tb (128 batch rows per block), 256 threads.
// LDS 43008 B -> 3 blocks/CU = 12 waves/CU.
// NOTE 1: min-waves arg MUST stay 2 — (…,4) caps VGPR at 64 -> spills (r2/r6/r9).
// NOTE 2: descent qq MUST be a compile-time unroll var — runtime-indexed
// ext_vector pr[] lowers to cndmask waterfalls, 15x VALU blowup (r9/r10).
__global__ __launch_bounds__(256, 2)
void k_main(const float* __restrict__ q,
            const float* __restrict__ tkey,
            const char* __restrict__ wsc,
            _Float16* __restrict__ pout)
{
    __shared__ _Float16 sA[128 * 64];   // q tile / leaf probs / epilogue transpose (swizzled, stride 64)
    __shared__ _Float16 sPT[128 * 72];  // node probs [batch][node], stride 72 halfs (16B-aligned rows)
    __shared__ _Float16 sB[64 * 64];    // kdiff (swizzled rows)

    const int tid  = threadIdx.x;
    const int w    = tid >> 6;          // 0..3
    const int lane = tid & 63;
    const int lm   = lane & 15;
    const int quad = lane >> 4;
    const int xcd  = blockIdx.x & 7;
    const int ix   = blockIdx.x >> 3;
    const int g    = xcd * 8 + (ix >> 4);   // 0..63
    const int tb   = ix & 15;               // 0..15

    // ---- in-kernel prefix kdiff -> sB rows 0..31 (one-time, swizzled) ----
    {
        const int j = tid >> 3, part = tid & 7;
        int gidx = -1;
        if (j < 6) {
            gidx = (1 << j) - 1 + (g >> (6 - j));
        } else if (j < 21) {
            const int u = j - 5;
            const int e = 31 - __builtin_clz(u);
            const int i = u - (1 << e);
            gidx = ((1 << (6 + e)) - 1) + (g << e) + i;
        }
        half8 out;
        if (gidx >= 0) {
            const floatx4* kp = (const floatx4*)(tkey + (size_t)gidx * 128) + part * 2;
            floatx4 a0 = kp[0], a1 = kp[1];
            floatx4 b0 = kp[16], b1 = kp[17];
            #pragma unroll
            for (int e = 0; e < 4; ++e) {
                out[e]     = (_Float16)(a0[e] - b0[e]);
                out[4 + e] = (_Float16)(a1[e] - b1[e]);
            }
        } else {
            #pragma unroll
            for (int e = 0; e < 8; ++e) out[e] = (_Float16)0.f;
        }
        *(half8*)(sB + j * 64 + ((part * 8) ^ ((j & 7) << 3))) = out;
    }

    // ---- q tile: 128 rows x 64 fp32 -> fp16 in sA (swizzled, stride 64) ----
    {
        const int r = tid >> 1, hh = tid & 1;
        const floatx4* qp = (const floatx4*)(q + (size_t)(tb * 128 + r) * 64 + hh * 32);
        const int sw = (r & 7) << 3;
        #pragma unroll
        for (int t4 = 0; t4 < 4; ++t4) {
            floatx4 f0 = qp[2 * t4], f1 = qp[2 * t4 + 1];
            half8 hv;
            #pragma unroll
            for (int e = 0; e < 4; ++e) { hv[e] = (_Float16)f0[e]; hv[4 + e] = (_Float16)f1[e]; }
            *(half8*)(sA + r * 64 + ((hh * 32 + t4 * 8) ^ sw)) = hv;
        }
    }
    __syncthreads();

    // q fragments (persist): wave w owns batch rows 32w+16m+lm, m=0..1
    half8 qA[2][2];
    #pragma unroll
    for (int m = 0; m < 2; ++m) {
        const int rA = 32 * w + 16 * m + lm;
        const int sw = (lm & 7) << 3;          // rA&7 == lm&7
        #pragma unroll
        for (int kt = 0; kt < 2; ++kt)
            qA[m][kt] = *(const half8*)(sA + rA * 64 + ((kt * 32 + quad * 8) ^ sw));
    }

    // prefix GEMM (nodes 0..31), swapped operands: D rows = nodes, cols = batch.
    {
        #pragma unroll
        for (int nt = 0; nt < 2; ++nt) {
            const int row = 16 * nt + lm;
            const int sw = (lm & 7) << 3;
            half8 bf0 = *(const half8*)(sB + row * 64 + ((quad * 8) ^ sw));
            half8 bf1 = *(const half8*)(sB + row * 64 + ((32 + quad * 8) ^ sw));
            floatx4 acc[2];
            #pragma unroll
            for (int m = 0; m < 2; ++m) {
                acc[m][0] = 0.f; acc[m][1] = 0.f; acc[m][2] = 0.f; acc[m][3] = 0.f;
                acc[m] = mfma16(bf0, qA[m][0], acc[m]);
                acc[m] = mfma16(bf1, qA[m][1], acc[m]);
            }
            #pragma unroll
            for (int m = 0; m < 2; ++m) {
                half4v ph;
                #pragma unroll
                for (int r = 0; r < 4; ++r) ph[r] = (_Float16)sigmf(acc[m][r]);
                *(half4v*)(sPT + (32 * w + 16 * m + lm) * 72 + 16 * nt + 4 * quad) = ph;
            }
        }
    }
    __syncthreads();

    // prefix probabilities -> registers (threads bb and bb+128 duplicate batch bb)
    const int bb = tid & 127;
    float pref = 1.f;
    #pragma unroll
    for (int d = 0; d < 6; ++d) {
        float pv = (float)sPT[bb * 72 + d];
        pref *= ((g >> (5 - d)) & 1) ? (1.f - pv) : pv;
    }
    const float p6    = (float)sPT[bb * 72 + 6];
    const float p7_0  = (float)sPT[bb * 72 + 7],  p7_1  = (float)sPT[bb * 72 + 8];
    const float p9_0  = (float)sPT[bb * 72 + 9],  p9_1  = (float)sPT[bb * 72 + 10];
    const float p9_2  = (float)sPT[bb * 72 + 11], p9_3  = (float)sPT[bb * 72 + 12];
    const float p13_0 = (float)sPT[bb * 72 + 13], p13_1 = (float)sPT[bb * 72 + 14];
    const float p13_2 = (float)sPT[bb * 72 + 15], p13_3 = (float)sPT[bb * 72 + 16];
    const float p13_4 = (float)sPT[bb * 72 + 17], p13_5 = (float)sPT[bb * 72 + 18];
    const float p13_6 = (float)sPT[bb * 72 + 19], p13_7 = (float)sPT[bb * 72 + 20];

    floatx4 O[2][4];
    #pragma unroll
    for (int m = 0; m < 2; ++m)
        #pragma unroll
        for (int nt = 0; nt < 4; ++nt) { O[m][nt][0]=0.f; O[m][nt][1]=0.f; O[m][nt][2]=0.f; O[m][nt][3]=0.f; }

    const int qh = tid >> 7;   // 0..1: which pair of qq quadrants this thread descends (wave-uniform)

    for (int sl = 0; sl < 16; ++sl) {
        const int s = (g << 4) + sl;

        // stage kdiff (8 KB: 4 waves x 2 KB, async DMA) + V fragments to regs
        {
            const char* kd = wsc + WS_KD + (size_t)s * 8192;
            gl_lds16(kd + w * 2048 +        lane * 16, sB + w * 1024);
            gl_lds16(kd + w * 2048 + 1024 + lane * 16, sB + w * 1024 + 512);
        }
        half8 vf[4][2];
        {
            const char* vt = wsc + WS_VT + (size_t)s * 8192;
            #pragma unroll
            for (int nt = 0; nt < 4; ++nt) {
                const int row = 16 * nt + lm;
                const int swz = (lm & 7) << 4;
                #pragma unroll
                for (int kt = 0; kt < 2; ++kt)
                    vf[nt][kt] = *(const half8*)(vt + row * 128 + ((kt * 64 + quad * 16) ^ swz));
            }
        }
        __syncthreads();   // B0: kd landed (barrier drains vmcnt)

        // GEMM1 (swapped) + sigmoid, fused per nt: probs -> sPT[batch][node]
        __builtin_amdgcn_s_setprio(1);
        #pragma unroll
        for (int nt = 0; nt < 4; ++nt) {
            const int row = 16 * nt + lm;
            const int sw = (lm & 7) << 3;
            half8 bf0 = *(const half8*)(sB + row * 64 + ((quad * 8) ^ sw));
            half8 bf1 = *(const half8*)(sB + row * 64 + ((32 + quad * 8) ^ sw));
            floatx4 acc[2];
            #pragma unroll
            for (int m = 0; m < 2; ++m) {
                acc[m][0] = 0.f; acc[m][1] = 0.f; acc[m][2] = 0.f; acc[m][3] = 0.f;
                acc[m] = mfma16(bf0, qA[m][0], acc[m]);
                acc[m] = mfma16(bf1, qA[m][1], acc[m]);
            }
            #pragma unroll
            for (int m = 0; m < 2; ++m) {
                half4v ph;
                #pragma unroll
                for (int r = 0; r < 4; ++r) ph[r] = (_Float16)sigmf(acc[m][r]);
                *(half4v*)(sPT + (32 * w + 16 * m + lm) * 72 + 16 * nt + 4 * quad) = ph;
            }
        }
        __builtin_amdgcn_s_setprio(0);
        __syncthreads();   // B1

        // P0 for this subtree from register prefix probs
        const int a0 = sl >> 3, a1 = sl >> 2, a2 = sl >> 1;
        float P0v = pref * (a0 ? (1.f - p6) : p6);
        { float v7 = a0 ? p7_1 : p7_0;                    P0v *= (a1 & 1) ? (1.f - v7) : v7; }
        { float v9 = (a1 == 0) ? p9_0 : (a1 == 1) ? p9_1 : (a1 == 2) ? p9_2 : p9_3;
                                                          P0v *= (a2 & 1) ? (1.f - v9) : v9; }
        { float vd = (a2 == 0) ? p13_0 : (a2 == 1) ? p13_1 : (a2 == 2) ? p13_2 : (a2 == 3) ? p13_3
                   : (a2 == 4) ? p13_4 : (a2 == 5) ? p13_5 : (a2 == 6) ? p13_6 : p13_7;
                                                          P0v *= (sl & 1) ? (1.f - vd) : vd; }

        // load batch bb's 64-node prob row: 8x ds_read_b128 (paired threads broadcast)
        half8 pr[8];
        #pragma unroll
        for (int t = 0; t < 8; ++t)
            pr[t] = *(const half8*)(sPT + bb * 72 + t * 8);
        #define PN(n) ((float)pr[(n) >> 3][(n) & 7])

        // leaf probabilities -> sA[bb][l] fp16.
        // qq is a COMPILE-TIME unroll var (rule #20); the wave-uniform guard
        // assigns qq 0,1 to waves 0-1 (qh=0) and qq 2,3 to waves 2-3 (qh=1).
        #pragma unroll
        for (int qq = 0; qq < 4; ++qq) {
            if ((qq >> 1) != qh) continue;
            float p0 = PN(0);
            float p1 = PN(1 + (qq >> 1));
            float P2 = P0v * (((qq >> 1) & 1) ? (1.f - p0) : p0)
                           * ((qq & 1) ? (1.f - p1) : p1);
            float p2 = PN(3 + qq);
            float A3[2]; A3[0] = P2 * p2; A3[1] = P2 * (1.f - p2);
            float A4[4];
            #pragma unroll
            for (int c = 0; c < 2; ++c) {
                float pv = PN(7 + 2 * qq + c);
                A4[2 * c] = A3[c] * pv; A4[2 * c + 1] = A3[c] * (1.f - pv);
            }
            float A5[8];
            #pragma unroll
            for (int n = 0; n < 4; ++n) {
                float pv = PN(15 + 4 * qq + n);
                A5[2 * n] = A4[n] * pv; A5[2 * n + 1] = A4[n] * (1.f - pv);
            }
            half8 lo, hi;
            #pragma unroll
            for (int n = 0; n < 8; ++n) {
                float pv = PN(31 + 8 * qq + n);
                float e0 = A5[n] * pv;
                float e1 = A5[n] * (1.f - pv);
                if (n < 4) { lo[2 * n] = (_Float16)e0; lo[2 * n + 1] = (_Float16)e1; }
                else       { hi[2 * (n - 4)] = (_Float16)e0; hi[2 * (n - 4) + 1] = (_Float16)e1; }
            }
            const int sw = (bb & 7) << 3;
            *(half8*)(sA + bb * 64 + ((16 * qq)     ^ sw)) = lo;
            *(half8*)(sA + bb * 64 + ((16 * qq + 8) ^ sw)) = hi;
        }
        #undef PN
        __syncthreads();   // B2

        // GEMM2: O += P @ V  (B-operand from registers)
        {
            half8 af[2][2];
            #pragma unroll
            for (int m = 0; m < 2; ++m) {
                const int rA = 32 * w + 16 * m + lm;
                const int sw = (lm & 7) << 3;
                #pragma unroll
                for (int kt = 0; kt < 2; ++kt)
                    af[m][kt] = *(const half8*)(sA + rA * 64 + ((kt * 32 + quad * 8) ^ sw));
            }
            __builtin_amdgcn_s_setprio(1);
            #pragma unroll
            for (int nt = 0; nt < 4; ++nt)
                #pragma unroll
                for (int kt = 0; kt < 2; ++kt) {
                    O[0][nt] = mfma16(af[0][kt], vf[nt][kt], O[0][nt]);
                    O[1][nt] = mfma16(af[1][kt], vf[nt][kt], O[1][nt]);
                }
            __builtin_amdgcn_s_setprio(0);
        }
    }

    // ---- epilogue: transpose O through sA (swizzled, stride 64), coalesced fp16 stores ----
    __syncthreads();
    #pragma unroll
    for (int m = 0; m < 2; ++m)
        #pragma unroll
        for (int nt = 0; nt < 4; ++nt)
            #pragma unroll
            for (int r = 0; r < 4; ++r) {
                const int row = 32 * w + 16 * m + 4 * quad + r;
                const int col = 16 * nt + lm;
                sA[row * 64 + (col ^ ((row & 7) << 3))] = (_Float16)O[m][nt][r];
            }
    __syncthreads();
    {
        const int row = tid >> 1, hh = tid & 1;
        _Float16* dst = pout + ((size_t)g * 2048 + tb * 128 + row) * 64 + hh * 32;
        const int sw = (row & 7) << 3;
        #pragma unroll
        for (int j = 0; j < 4; ++j)
            *(half8*)(dst + j * 8) = *(const half8*)(sA + row * 64 + ((hh * 32 + j * 8) ^ sw));
    }
}

// ================= kernel 3: reduce 64 fp16 partials -> fp32 out =================
__global__ __launch_bounds__(256)
void k_reduce(const _Float16* __restrict__ part, float* __restrict__ outp)
{
    const int idx = blockIdx.x * 256 + threadIdx.x;  // 0..32767
    float s0 = 0.f, s1 = 0.f, s2 = 0.f, s3 = 0.f;
    #pragma unroll 8
    for (int gg = 0; gg < 64; ++gg) {
        half4v v = *(const half4v*)(part + (size_t)gg * 131072 + (size_t)idx * 4);
        s0 += (float)v[0]; s1 += (float)v[1]; s2 += (float)v[2]; s3 += (float)v[3];
    }
    floatx4 o; o[0] = s0; o[1] = s1; o[2] = s2; o[3] = s3;
    *(floatx4*)(outp + (size_t)idx * 4) = o;
}

extern "C" void kernel_launch(void* const* d_in, const int* in_sizes, int n_in,
                              void* d_out, int out_size, void* d_ws, size_t ws_size,
                              hipStream_t stream)
{
    const float* q  = (const float*)d_in[0];
    const float* tk = (const float*)d_in[1];
    const float* tv = (const float*)d_in[2];
    float* outp = (float*)d_out;
    char*  ws   = (char*)d_ws;
    _Float16* partp = (_Float16*)(ws + WS_PART);

    k_prep  <<<dim3(1024), dim3(256), 0, stream>>>(tk, tv, ws);
    k_main  <<<dim3(1024), dim3(256), 0, stream>>>(q, tk, ws, partp);
    k_reduce<<<dim3(128),  dim3(256), 0, stream>>>(partp, outp);
}

// Round 12
// 164.715 us; speedup vs baseline: 7.6831x; 1.0717x over previous
//
#include <hip/hip_runtime.h>

#define LOG2E 1.44269504088896f

typedef _Float16 half8  __attribute__((ext_vector_type(8)));
typedef _Float16 half4v __attribute__((ext_vector_type(4)));
typedef float    floatx4 __attribute__((ext_vector_type(4)));

// ---------------- workspace layout (bytes) ----------------
// kd:       [1024 subtrees][8 frags][64 lanes][16B]  fragment-ordered  (8 MB)
// vt:       [1024 subtrees][8 frags][64 lanes][16B]  fragment-ordered  (8 MB)
// partials: [64 groups][2048 b][64 v] fp16                             (16.78 MB)
// total = 33554432 bytes exactly (proven available)
#define WS_KD   0u
#define WS_VT   8388608u
#define WS_PART 16777216u

__device__ __forceinline__ floatx4 mfma16(half8 a, half8 b, floatx4 c) {
    return __builtin_amdgcn_mfma_f32_16x16x32_f16(a, b, c, 0, 0, 0);
}

__device__ __forceinline__ float sigmf(float d) {
    return __builtin_amdgcn_rcpf(1.0f + __builtin_amdgcn_exp2f(d * (-LOG2E)));
}

// intra-wave LDS fence: drain ds ops, pin ordering (rule #18)
__device__ __forceinline__ void wave_lds_fence() {
    asm volatile("s_waitcnt lgkmcnt(0)" ::: "memory");
    __builtin_amdgcn_sched_barrier(0);
}

// ================= kernel 1: prep (kd + vt, fragment-ordered) =================
// Fragment layout per subtree (8192 B): frag f = nt*2+kt at f*1024, lane (quad<<4|lm)
// holds halfs [row=16nt+lm][kt*32+quad*8 .. +8]. GEMM operand loads are then
// single coalesced 16B/lane global loads.
__global__ __launch_bounds__(256)
void k_prep(const float* __restrict__ tkey, const float* __restrict__ tval,
            char* __restrict__ ws)
{
    __shared__ _Float16 sT[64 * 72];   // [dim][leaf], +8 pad
    const int bid = blockIdx.x, tid = threadIdx.x;

    // ---- vt for subtree s = bid: transpose V -> [dim][leaf], then frag-order ----
    {
        const int l = tid >> 2, part = tid & 3;
        const floatx4* vp = (const floatx4*)(tval + ((size_t)bid * 64 + l) * 64) + part * 4;
        #pragma unroll
        for (int t4 = 0; t4 < 4; ++t4) {
            floatx4 f = vp[t4];
            #pragma unroll
            for (int e = 0; e < 4; ++e)
                sT[(part * 16 + t4 * 4 + e) * 72 + l] = (_Float16)f[e];
        }
    }
    __syncthreads();
    {
        const int v = tid >> 2, q4 = tid & 3;       // row v, chunks u=2q4, 2q4+1
        half8 x0 = *(const half8*)(sT + v * 72 + 16 * q4);
        half8 x1 = *(const half8*)(sT + v * 72 + 16 * q4 + 8);
        char* base = ws + WS_VT + (size_t)bid * 8192;
        const int nt = v >> 4, lm = v & 15;
        const int u0 = 2 * q4, u1 = 2 * q4 + 1;
        *(half8*)(base + (nt * 2 + (u0 >> 2)) * 1024 + (((u0 & 3) << 4) | lm) * 16) = x0;
        *(half8*)(base + (nt * 2 + (u1 >> 2)) * 1024 + (((u1 & 3) << 4) | lm) * 16) = x1;
    }

    // ---- kd: 2 items per thread (1024 blocks x 512 = 524288 items) ----
    #pragma unroll
    for (int k = 0; k < 2; ++k) {
        const int gt  = bid * 512 + k * 256 + tid;
        const int rid = gt >> 3, part = gt & 7;     // chunk u = part
        const int s = rid >> 6, j = rid & 63;
        const size_t dst = (size_t)WS_KD + (size_t)s * 8192
                         + ((j >> 4) * 2 + (part >> 2)) * 1024
                         + (((part & 3) << 4) | (j & 15)) * 16;
        half8 out;
        if (j < 63) {
            const int u = j + 1;
            const int f = 31 - __builtin_clz(u);
            const int i = u - (1 << f);
            const int gidx = ((1 << (10 + f)) - 1) + (s << f) + i;
            const floatx4* kp = (const floatx4*)(tkey + (size_t)gidx * 128) + part * 2;
            floatx4 a0 = kp[0], a1 = kp[1];
            floatx4 b0 = kp[16], b1 = kp[17];
            #pragma unroll
            for (int e = 0; e < 4; ++e) {
                out[e]     = (_Float16)(a0[e] - b0[e]);
                out[4 + e] = (_Float16)(a1[e] - b1[e]);
            }
        } else {
            #pragma unroll
            for (int e = 0; e < 8; ++e) out[e] = (_Float16)0.f;
        }
        *(half8*)(ws + dst) = out;
    }
}

// ================= kernel 2: main fused attention — barrier-free main loop =================
// grid 512 = 64 g x 8 tb (256 batch rows per block), 256 threads (4 waves).
// All in-loop LDS traffic is wave-private (sPT/sA rows 64w..64w+63); GEMM operands
// (kd, vt) load directly from global (L2-resident, fragment-ordered) -> no sB, no
// block barriers in the loop, waves free-run. 2 intra-wave lgkmcnt fences per iter.
// LDS 69632 B -> 2 blocks/CU. min-waves arg stays 2 (VGPR-64 spill trap, r2/r6/r9).
__global__ __launch_bounds__(256, 2)
void k_main(const float* __restrict__ q,
            const float* __restrict__ tkey,
            const char* __restrict__ wsc,
            _Float16* __restrict__ pout)
{
    __shared__ _Float16 sA[256 * 64];   // q tile / prefix kdiff (rows 0..31) / leaf probs / epilogue
    __shared__ _Float16 sPT[256 * 72];  // node probs [batch][node], stride 72 halfs

    const int tid  = threadIdx.x;
    const int w    = tid >> 6;          // 0..3
    const int lane = tid & 63;
    const int lm   = lane & 15;
    const int quad = lane >> 4;
    const int xcd  = blockIdx.x & 7;
    const int ix   = blockIdx.x >> 3;
    const int g    = xcd * 8 + (ix >> 3);   // 0..63
    const int tb   = ix & 7;                // 0..7

    // ---- prologue: q tile -> sA (swizzled, stride 64) ----
    {
        const int r = tid;
        const floatx4* qp = (const floatx4*)(q + (size_t)(tb * 256 + r) * 64);
        const int sw = (r & 7) << 3;
        #pragma unroll
        for (int t4 = 0; t4 < 8; ++t4) {
            floatx4 f0 = qp[2 * t4], f1 = qp[2 * t4 + 1];
            half8 hv;
            #pragma unroll
            for (int e = 0; e < 4; ++e) { hv[e] = (_Float16)f0[e]; hv[4 + e] = (_Float16)f1[e]; }
            *(half8*)(sA + r * 64 + ((t4 * 8) ^ sw)) = hv;
        }
    }
    __syncthreads();

    // q fragments (persist): wave w owns batch rows 64w+16m+lm, m=0..3
    half8 qA[4][2];
    #pragma unroll
    for (int m = 0; m < 4; ++m) {
        const int rA = 64 * w + 16 * m + lm;
        const int sw = (lm & 7) << 3;
        #pragma unroll
        for (int kt = 0; kt < 2; ++kt)
            qA[m][kt] = *(const half8*)(sA + rA * 64 + ((kt * 32 + quad * 8) ^ sw));
    }
    __syncthreads();   // all qA reads done before rows 0..31 are overwritten

    // ---- prefix kdiff -> sA rows 0..31 (one-time, swizzled; same layout as old sB) ----
    {
        const int j = tid >> 3, part = tid & 7;
        int gidx = -1;
        if (j < 6) {
            gidx = (1 << j) - 1 + (g >> (6 - j));
        } else if (j < 21) {
            const int u = j - 5;
            const int e = 31 - __builtin_clz(u);
            const int i = u - (1 << e);
            gidx = ((1 << (6 + e)) - 1) + (g << e) + i;
        }
        half8 out;
        if (gidx >= 0) {
            const floatx4* kp = (const floatx4*)(tkey + (size_t)gidx * 128) + part * 2;
            floatx4 a0 = kp[0], a1 = kp[1];
            floatx4 b0 = kp[16], b1 = kp[17];
            #pragma unroll
            for (int e = 0; e < 4; ++e) {
                out[e]     = (_Float16)(a0[e] - b0[e]);
                out[4 + e] = (_Float16)(a1[e] - b1[e]);
            }
        } else {
            #pragma unroll
            for (int e = 0; e < 8; ++e) out[e] = (_Float16)0.f;
        }
        *(half8*)(sA + j * 64 + ((part * 8) ^ ((j & 7) << 3))) = out;
    }
    __syncthreads();

    // prefix GEMM (nodes 0..31), swapped operands -> sigmoid -> sPT[batch][node]
    {
        #pragma unroll
        for (int nt = 0; nt < 2; ++nt) {
            const int row = 16 * nt + lm;
            const int sw = (lm & 7) << 3;
            half8 bf0 = *(const half8*)(sA + row * 64 + ((quad * 8) ^ sw));
            half8 bf1 = *(const half8*)(sA + row * 64 + ((32 + quad * 8) ^ sw));
            floatx4 acc[4];
            #pragma unroll
            for (int m = 0; m < 4; ++m) {
                acc[m][0] = 0.f; acc[m][1] = 0.f; acc[m][2] = 0.f; acc[m][3] = 0.f;
                acc[m] = mfma16(bf0, qA[m][0], acc[m]);
                acc[m] = mfma16(bf1, qA[m][1], acc[m]);
            }
            #pragma unroll
            for (int m = 0; m < 4; ++m) {
                half4v ph;
                #pragma unroll
                for (int r = 0; r < 4; ++r) ph[r] = (_Float16)sigmf(acc[m][r]);
                *(half4v*)(sPT + (64 * w + 16 * m + lm) * 72 + 16 * nt + 4 * quad) = ph;
            }
        }
    }
    __syncthreads();

    // prefix probabilities -> registers (row bb = tid, wave-private)
    const int bb = tid;
    float pref = 1.f;
    #pragma unroll
    for (int d = 0; d < 6; ++d) {
        float pv = (float)sPT[bb * 72 + d];
        pref *= ((g >> (5 - d)) & 1) ? (1.f - pv) : pv;
    }
    const float p6    = (float)sPT[bb * 72 + 6];
    const float p7_0  = (float)sPT[bb * 72 + 7],  p7_1  = (float)sPT[bb * 72 + 8];
    const float p9_0  = (float)sPT[bb * 72 + 9],  p9_1  = (float)sPT[bb * 72 + 10];
    const float p9_2  = (float)sPT[bb * 72 + 11], p9_3  = (float)sPT[bb * 72 + 12];
    const float p13_0 = (float)sPT[bb * 72 + 13], p13_1 = (float)sPT[bb * 72 + 14];
    const float p13_2 = (float)sPT[bb * 72 + 15], p13_3 = (float)sPT[bb * 72 + 16];
    const float p13_4 = (float)sPT[bb * 72 + 17], p13_5 = (float)sPT[bb * 72 + 18];
    const float p13_6 = (float)sPT[bb * 72 + 19], p13_7 = (float)sPT[bb * 72 + 20];

    floatx4 O[4][4];
    #pragma unroll
    for (int m = 0; m < 4; ++m)
        #pragma unroll
        for (int nt = 0; nt < 4; ++nt) { O[m][nt][0]=0.f; O[m][nt][1]=0.f; O[m][nt][2]=0.f; O[m][nt][3]=0.f; }

    // ================= barrier-free main loop =================
    for (int sl = 0; sl < 16; ++sl) {
        const int s = (g << 4) + sl;

        // operand fragments direct from global (L2-hot, coalesced 16B/lane)
        const char* kdp = wsc + WS_KD + (size_t)s * 8192;
        const char* vtp = wsc + WS_VT + (size_t)s * 8192;
        half8 bfr[4][2], vf[4][2];
        #pragma unroll
        for (int nt = 0; nt < 4; ++nt)
            #pragma unroll
            for (int kt = 0; kt < 2; ++kt) {
                bfr[nt][kt] = *(const half8*)(kdp + (nt * 2 + kt) * 1024 + lane * 16);
                vf[nt][kt]  = *(const half8*)(vtp + (nt * 2 + kt) * 1024 + lane * 16);
            }

        // GEMM1 (swapped) + sigmoid -> sPT (wave-private rows)
        __builtin_amdgcn_s_setprio(1);
        #pragma unroll
        for (int nt = 0; nt < 4; ++nt) {
            floatx4 acc[4];
            #pragma unroll
            for (int m = 0; m < 4; ++m) {
                acc[m][0] = 0.f; acc[m][1] = 0.f; acc[m][2] = 0.f; acc[m][3] = 0.f;
                acc[m] = mfma16(bfr[nt][0], qA[m][0], acc[m]);
                acc[m] = mfma16(bfr[nt][1], qA[m][1], acc[m]);
            }
            #pragma unroll
            for (int m = 0; m < 4; ++m) {
                half4v ph;
                #pragma unroll
                for (int r = 0; r < 4; ++r) ph[r] = (_Float16)sigmf(acc[m][r]);
                *(half4v*)(sPT + (64 * w + 16 * m + lm) * 72 + 16 * nt + 4 * quad) = ph;
            }
        }
        __builtin_amdgcn_s_setprio(0);
        wave_lds_fence();   // sPT writes visible to own wave's cross-lane reads

        // P0 for this subtree from register prefix probs
        const int a0 = sl >> 3, a1 = sl >> 2, a2 = sl >> 1;
        float P0v = pref * (a0 ? (1.f - p6) : p6);
        { float v7 = a0 ? p7_1 : p7_0;                    P0v *= (a1 & 1) ? (1.f - v7) : v7; }
        { float v9 = (a1 == 0) ? p9_0 : (a1 == 1) ? p9_1 : (a1 == 2) ? p9_2 : p9_3;
                                                          P0v *= (a2 & 1) ? (1.f - v9) : v9; }
        { float vd = (a2 == 0) ? p13_0 : (a2 == 1) ? p13_1 : (a2 == 2) ? p13_2 : (a2 == 3) ? p13_3
                   : (a2 == 4) ? p13_4 : (a2 == 5) ? p13_5 : (a2 == 6) ? p13_6 : p13_7;
                                                          P0v *= (sl & 1) ? (1.f - vd) : vd; }

        // own 64-node prob row: 8x ds_read_b128 (wave-private)
        half8 pr[8];
        #pragma unroll
        for (int t = 0; t < 8; ++t)
            pr[t] = *(const half8*)(sPT + bb * 72 + t * 8);
        #define PN(n) ((float)pr[(n) >> 3][(n) & 7])

        // leaf probabilities -> sA[bb][l] fp16 (compile-time indices)
        #pragma unroll
        for (int qq = 0; qq < 4; ++qq) {
            float p0 = PN(0);
            float p1 = PN(1 + (qq >> 1));
            float P2 = P0v * (((qq >> 1) & 1) ? (1.f - p0) : p0)
                           * ((qq & 1) ? (1.f - p1) : p1);
            float p2 = PN(3 + qq);
            float A3[2]; A3[0] = P2 * p2; A3[1] = P2 * (1.f - p2);
            float A4[4];
            #pragma unroll
            for (int c = 0; c < 2; ++c) {
                float pv = PN(7 + 2 * qq + c);
                A4[2 * c] = A3[c] * pv; A4[2 * c + 1] = A3[c] * (1.f - pv);
            }
            float A5[8];
            #pragma unroll
            for (int n = 0; n < 4; ++n) {
                float pv = PN(15 + 4 * qq + n);
                A5[2 * n] = A4[n] * pv; A5[2 * n + 1] = A4[n] * (1.f - pv);
            }
            half8 lo, hi;
            #pragma unroll
            for (int n = 0; n < 8; ++n) {
                float pv = PN(31 + 8 * qq + n);
                float e0 = A5[n] * pv;
                float e1 = A5[n] * (1.f - pv);
                if (n < 4) { lo[2 * n] = (_Float16)e0; lo[2 * n + 1] = (_Float16)e1; }
                else       { hi[2 * (n - 4)] = (_Float16)e0; hi[2 * (n - 4) + 1] = (_Float16)e1; }
            }
            const int sw = (bb & 7) << 3;
            *(half8*)(sA + bb * 64 + ((16 * qq)     ^ sw)) = lo;
            *(half8*)(sA + bb * 64 + ((16 * qq + 8) ^ sw)) = hi;
        }
        #undef PN
        wave_lds_fence();   // sA leaf writes visible to own wave's af reads

        // GEMM2: O += P @ V  (A from wave-private sA, B from registers)
        {
            half8 af[4][2];
            #pragma unroll
            for (int m = 0; m < 4; ++m) {
                const int rA = 64 * w + 16 * m + lm;
                const int sw = (lm & 7) << 3;
                #pragma unroll
                for (int kt = 0; kt < 2; ++kt)
                    af[m][kt] = *(const half8*)(sA + rA * 64 + ((kt * 32 + quad * 8) ^ sw));
            }
            __builtin_amdgcn_s_setprio(1);
            #pragma unroll
            for (int nt = 0; nt < 4; ++nt)
                #pragma unroll
                for (int kt = 0; kt < 2; ++kt) {
                    O[0][nt] = mfma16(af[0][kt], vf[nt][kt], O[0][nt]);
                    O[1][nt] = mfma16(af[1][kt], vf[nt][kt], O[1][nt]);
                    O[2][nt] = mfma16(af[2][kt], vf[nt][kt], O[2][nt]);
                    O[3][nt] = mfma16(af[3][kt], vf[nt][kt], O[3][nt]);
                }
            __builtin_amdgcn_s_setprio(0);
        }
    }

    // ---- epilogue: transpose O through sA (swizzled), coalesced fp16 stores ----
    __syncthreads();
    #pragma unroll
    for (int m = 0; m < 4; ++m)
        #pragma unroll
        for (int nt = 0; nt < 4; ++nt)
            #pragma unroll
            for (int r = 0; r < 4; ++r) {
                const int row = 64 * w + 16 * m + 4 * quad + r;
                const int col = 16 * nt + lm;
                sA[row * 64 + (col ^ ((row & 7) << 3))] = (_Float16)O[m][nt][r];
            }
    __syncthreads();
    {
        const int row = tid;
        _Float16* dst = pout + ((size_t)g * 2048 + tb * 256 + row) * 64;
        const int sw = (row & 7) << 3;
        #pragma unroll
        for (int j = 0; j < 8; ++j)
            *(half8*)(dst + j * 8) = *(const half8*)(sA + row * 64 + ((j * 8) ^ sw));
    }
}

// ================= kernel 3: reduce 64 fp16 partials -> fp32 out =================
__global__ __launch_bounds__(256)
void k_reduce(const _Float16* __restrict__ part, float* __restrict__ outp)
{
    const int idx = blockIdx.x * 256 + threadIdx.x;  // 0..32767
    float s0 = 0.f, s1 = 0.f, s2 = 0.f, s3 = 0.f;
    #pragma unroll 8
    for (int gg = 0; gg < 64; ++gg) {
        half4v v = *(const half4v*)(part + (size_t)gg * 131072 + (size_t)idx * 4);
        s0 += (float)v[0]; s1 += (float)v[1]; s2 += (float)v[2]; s3 += (float)v[3];
    }
    floatx4 o; o[0] = s0; o[1] = s1; o[2] = s2; o[3] = s3;
    *(floatx4*)(outp + (size_t)idx * 4) = o;
}

extern "C" void kernel_launch(void* const* d_in, const int* in_sizes, int n_in,
                              void* d_out, int out_size, void* d_ws, size_t ws_size,
                              hipStream_t stream)
{
    const float* q  = (const float*)d_in[0];
    const float* tk = (const float*)d_in[1];
    const float* tv = (const float*)d_in[2];
    float* outp = (float*)d_out;
    char*  ws   = (char*)d_ws;
    _Float16* partp = (_Float16*)(ws + WS_PART);

    k_prep  <<<dim3(1024), dim3(256), 0, stream>>>(tk, tv, ws);
    k_main  <<<dim3(512),  dim3(256), 0, stream>>>(q, tk, ws, partp);
    k_reduce<<<dim3(128),  dim3(256), 0, stream>>>(partp, outp);
}